// Round 6
// baseline (539.938 us; speedup 1.0000x reference)
//
#include <hip/hip_runtime.h>
#include <math.h>
#include <stdint.h>

#define F_K 802816          // 64*112*112
#define NSL 56              // k-slices
#define KSL 14336           // F_K / NSL
#define NTL 28              // tiles per slice (KSL / KT)
#define KT  512             // k per tile
#define PRED_OFF 12845056
#define NORM_OFF 12845568   // PRED_OFF + 512

#define AS3 __attribute__((address_space(3)))
#define AS1 __attribute__((address_space(1)))

// async global->LDS, 16B per lane; LDS dest = base + lane*16 (HW), src per-lane.
__device__ __forceinline__ void gload16(const float* gsrc, float* ldsbase) {
  __builtin_amdgcn_global_load_lds((const AS1 uint32_t*)gsrc, (AS3 uint32_t*)ldsbase, 16, 0, 0);
}

// ---------------- Kernel 1: panel-streaming GEMM  part[s][b][n] ------------------
// grid 896 = 56 k-slices x 16 n-panels (8 rows). bid&7 == s%8 -> all 16 panels of
// a slice on one XCD (x-chunk fetched from HBM once; L3 backstop otherwise).
// Wave w owns k-quarter [128w,128w+128) of each 512-k tile:
//  - W: global->REGISTER, 512B contiguous per row-segment, rows walked
//    sequentially in k across tiles (page-sequential DRAM access).
//  - x: wave-private LDS [16 b][128 k], staged in 1KB-contiguous gload16 calls.
// Thread (hi=lane>>5, kx=lane&31): rows {2c+hi}, k-float4 kx; acc[16 b][4 c].
__global__ __launch_bounds__(256, 4) void k_gemm1(const float* __restrict__ x,
                                                  const float* __restrict__ w1,
                                                  float* __restrict__ part) {
  __shared__ __align__(16) float xs[4 * 2048];   // 32 KB, wave-private quarters
  const int t = threadIdx.x;
  const int wave = t >> 6, lane = t & 63;
  const int hi = lane >> 5, kx = lane & 31;
  const int bid = blockIdx.x;
  const int xcd = bid & 7, j = bid >> 3;
  const int p = j & 15, s = xcd + 8 * (j >> 4);

  const size_t kb0 = (size_t)s * KSL + 128 * wave + 4 * kx;  // lane's k base
  const float* wptr = w1 + (size_t)(8 * p + hi) * F_K + kb0; // row 8p+hi (+2c*F_K)
  const float* xptr = x + (size_t)hi * F_K + kb0;            // row hi (+2cc*F_K)
  float* xw = xs + wave * 2048;                              // wave's [16][128]

  float acc[16][4];
#pragma unroll
  for (int b = 0; b < 16; ++b)
#pragma unroll
    for (int c = 0; c < 4; ++c) acc[b][c] = 0.f;

#define STAGE_X()                                                     \
  {                                                                   \
    _Pragma("unroll") for (int cc = 0; cc < 8; ++cc)                  \
        gload16(xptr + (size_t)(2 * cc) * F_K, xw + cc * 256);        \
  }
#define LOADW(dst, OFF)                                               \
  {                                                                   \
    _Pragma("unroll") for (int c = 0; c < 4; ++c)                     \
        dst[c] = *reinterpret_cast<const float4*>(                    \
            wptr + (size_t)(2 * c) * F_K + (OFF));                    \
  }
#define COMP(WREG)                                                    \
  {                                                                   \
    _Pragma("unroll") for (int b = 0; b < 16; ++b) {                  \
      float4 xv = *reinterpret_cast<const float4*>(&xw[b * 128 + 4 * kx]); \
      _Pragma("unroll") for (int c = 0; c < 4; ++c) {                 \
        acc[b][c] += WREG[c].x * xv.x; acc[b][c] += WREG[c].y * xv.y; \
        acc[b][c] += WREG[c].z * xv.z; acc[b][c] += WREG[c].w * xv.w; \
      }                                                               \
    }                                                                 \
  }

  float4 wA[4], wB[4];
  STAGE_X();        // tile 0 x (8 loads)
  LOADW(wA, 0);     // tile 0 W (4 loads)

  for (int kt = 0; kt < NTL; kt += 2) {
    // ---- even tile (wA) ----
    LOADW(wB, KT);                                   // prefetch W(kt+1)
    asm volatile("s_waitcnt vmcnt(4)" ::: "memory"); // x(kt)+W(kt) landed
    __builtin_amdgcn_sched_barrier(0);
    COMP(wA);
    __builtin_amdgcn_sched_barrier(0);
    asm volatile("s_waitcnt lgkmcnt(0)" ::: "memory");
    __builtin_amdgcn_sched_barrier(0);
    wptr += KT; xptr += KT;
    STAGE_X();                                       // x(kt+1), overwrites xw
    // ---- odd tile (wB) ----
    if (kt + 2 < NTL) {
      LOADW(wA, KT);
      asm volatile("s_waitcnt vmcnt(4)" ::: "memory");
    } else {
      asm volatile("s_waitcnt vmcnt(0)" ::: "memory");
    }
    __builtin_amdgcn_sched_barrier(0);
    COMP(wB);
    __builtin_amdgcn_sched_barrier(0);
    asm volatile("s_waitcnt lgkmcnt(0)" ::: "memory");
    __builtin_amdgcn_sched_barrier(0);
    wptr += KT; xptr += KT;
    if (kt + 2 < NTL) STAGE_X();
  }
#undef STAGE_X
#undef LOADW
#undef COMP

  // in-wave butterfly over the 32 kx positions
#pragma unroll
  for (int b = 0; b < 16; ++b)
#pragma unroll
    for (int c = 0; c < 4; ++c) {
      float v = acc[b][c];
      v += __shfl_xor(v, 1);
      v += __shfl_xor(v, 2);
      v += __shfl_xor(v, 4);
      v += __shfl_xor(v, 8);
      v += __shfl_xor(v, 16);
      acc[b][c] = v;
    }
  // red region inside the wave's OWN xs quarter (other waves may still compute)
  if (kx < 16) {
#pragma unroll
    for (int c = 0; c < 4; ++c)
      xs[wave * 2048 + kx * 8 + 2 * c + hi] = acc[kx][c];
  }
  __syncthreads();
  if (t < 128) {   // t = b*8 + r
    float v = xs[t] + xs[2048 + t] + xs[4096 + t] + xs[6144 + t];
    part[(size_t)s * 2048 + (size_t)(t >> 3) * 128 + 8 * p + (t & 7)] = v;
  }
}

// ---------------- Kernel 2a: reduce 56 slice-partials -> p2[16][128] ------------
__global__ __launch_bounds__(256) void k_red(const float* __restrict__ part,
                                             float* __restrict__ p2) {
  int idx = blockIdx.x * 256 + threadIdx.x;   // 0..2047
  const float* p = part + idx;
  float ssum = 0.f;
#pragma unroll 8
  for (int s = 0; s < NSL; ++s) ssum += p[(size_t)s * 2048];
  p2[idx] = ssum;
}

// ---------------- Kernel 2b: small heads + TPS solve (1 wave / batch) -----------
__global__ __launch_bounds__(64) void k_small(const float* __restrict__ p2,
    const float* __restrict__ b1, const float* __restrict__ W2, const float* __restrict__ b2,
    const float* __restrict__ W3, const float* __restrict__ b3,
    const float* __restrict__ lmean, const float* __restrict__ scales,
    float* __restrict__ dout_pred, float* __restrict__ coef, float* __restrict__ norms) {
  const int b = blockIdx.x, lane = threadIdx.x;
  __shared__ float o[128], dflat[32], fl[32], A[19][22], farr[19], sol[19][2];

  o[lane]      = p2[b * 128 + lane]      + b1[lane];
  o[lane + 64] = p2[b * 128 + 64 + lane] + b1[64 + lane];
  __syncthreads();

  // lanes 0..31: out@W2^T; lanes 32..63: out@W3^T
  const int j = lane & 31;
  const float* Wm = (lane < 32) ? (W2 + j * 128) : (W3 + j * 128);
  float acc = 0.f;
#pragma unroll 4
  for (int n = 0; n < 128; ++n) acc += o[n] * Wm[n];
  float other = __shfl(acc, j + 32);
  float sc = scales[b];
  float dspv = 0.f;
  if (lane < 32) {
    float predv = acc + b2[j] + lmean[j];
    dspv = (other + b3[j]) * sc;
    dout_pred[b * 32 + j] = predv;
    dflat[j] = predv + dspv;   // dst (flat y,x pairs)
    fl[j] = dspv;              // flows = dst - src
  }
  float s2 = (lane < 32) ? dspv * dspv : 0.f;
  for (int off = 32; off; off >>= 1) s2 += __shfl_xor(s2, off);
  if (lane == 0) norms[b] = sqrtf(s2);
  __syncthreads();

  // build augmented TPS system A[19][19+2]
  for (int cell = lane; cell < 19 * 21; cell += 64) {
    int r = cell / 21, c = cell - (cell / 21) * 21;
    float v;
    if (r < 16) {
      if (c < 16) {
        float dy = dflat[2*r] - dflat[2*c], dx = dflat[2*r+1] - dflat[2*c+1];
        float d2 = dy * dy + dx * dx;
        v = 0.5f * d2 * logf(fmaxf(d2, 1e-10f));
        if (r == c) v += 1e-6f;
      } else if (c == 16) v = dflat[2*r];
      else if (c == 17) v = dflat[2*r+1];
      else if (c == 18) v = 1.0f;
      else if (c == 19) v = fl[2*r];
      else               v = fl[2*r+1];
    } else {
      int rr = r - 16;
      if (c < 16) v = (rr == 0) ? dflat[2*c] : (rr == 1) ? dflat[2*c+1] : 1.0f;
      else        v = 0.0f;
    }
    A[r][c] = v;
  }
  __syncthreads();

  // Gaussian elimination with partial pivoting
  for (int k = 0; k < 19; ++k) {
    float av = (lane >= k && lane < 19) ? fabsf(A[lane][k]) : -1.0f;
    int idx = lane;
    for (int off = 32; off; off >>= 1) {
      float v2 = __shfl_xor(av, off);
      int  i2 = __shfl_xor(idx, off);
      if (v2 > av) { av = v2; idx = i2; }
    }
    idx = __shfl(idx, 0);   // consistent pivot across lanes
    if (idx != k && lane < 21) {
      float tmp = A[k][lane]; A[k][lane] = A[idx][lane]; A[idx][lane] = tmp;
    }
    __syncthreads();
    float invp = 1.0f / A[k][k];
    if (lane < 19) farr[lane] = (lane > k) ? A[lane][k] * invp : 0.0f;
    __syncthreads();
    int nr = 18 - k, nc = 20 - k;
    for (int cell = lane; cell < nr * nc; cell += 64) {
      int i = k + 1 + cell / nc, jj = k + 1 + cell % nc;
      A[i][jj] -= farr[i] * A[k][jj];
    }
    __syncthreads();
  }
  // back substitution (2 rhs columns in parallel)
  for (int k = 18; k >= 0; --k) {
    if (lane < 2) sol[k][lane] = A[k][19 + lane] / A[k][k];
    __syncthreads();
    if (lane < 2 * k) {
      int i = lane >> 1, c = lane & 1;
      A[i][19 + c] -= A[i][k] * sol[k][c];
    }
    __syncthreads();
  }
  // store coefficients: [0..31]=w, [32..37]=v, [38..69]=dst
  float* cf = coef + b * 80;
  if (lane < 32) { cf[lane] = sol[lane >> 1][lane & 1]; cf[38 + lane] = dflat[lane]; }
  else if (lane < 38) cf[lane] = sol[16 + ((lane - 32) >> 1)][(lane - 32) & 1];
}

// ---------------- Kernel 3: dense TPS flow + bilinear warp + NHWC->NCHW ---------
__global__ __launch_bounds__(256) void k_warp(const float* __restrict__ img,
                                              const float* __restrict__ coef,
                                              const float* __restrict__ norms,
                                              float* __restrict__ out) {
  const int bid = blockIdx.x;
  const int b = bid / 112, y = bid - (bid / 112) * 112;
  const int t = threadIdx.x;
  __shared__ float qy[112], qx[112];
  __shared__ float cw[32], cv[6], cd[32];
  __shared__ float tile[64][113];   // pad 113 -> conflict-free transposed access

  if (bid == 0 && t == 0) {         // finalize landmarks_norm
    float s = 0.f;
    for (int i = 0; i < 16; ++i) s += norms[i];
    out[NORM_OFF] = s * (1.0f / 16.0f);
  }
  const float* cf = coef + b * 80;
  if (t < 70) {
    float v = cf[t];
    if (t < 32) cw[t] = v;
    else if (t < 38) cv[t - 32] = v;
    else cd[t - 38] = v;
  }
  __syncthreads();

  // phase A: per-pixel TPS flow -> query coords
  if (t < 112) {
    float fy = (float)y, fx = (float)t;
    float s0 = cv[0] * fy + cv[2] * fx + cv[4];
    float s1 = cv[1] * fy + cv[3] * fx + cv[5];
#pragma unroll
    for (int i = 0; i < 16; ++i) {
      float dy = fy - cd[2 * i], dx = fx - cd[2 * i + 1];
      float d2 = dy * dy + dx * dx;
      float ph = 0.5f * d2 * logf(fmaxf(d2, 1e-10f));
      s0 += ph * cw[2 * i];
      s1 += ph * cw[2 * i + 1];
    }
    qy[t] = fy - s0;
    qx[t] = fx - s1;
  }
  __syncthreads();

  // phase B: bilinear gather, lane = channel (coalesced 256B per neighbor)
  const int wave = t >> 6, lane = t & 63;
#pragma unroll 4
  for (int p = 0; p < 28; ++p) {
    int xx = wave * 28 + p;
    float fy = qy[xx], fx = qx[xx];
    float y0f = fminf(fmaxf(floorf(fy), 0.f), 110.f);
    float x0f = fminf(fmaxf(floorf(fx), 0.f), 110.f);
    float ay = fminf(fmaxf(fy - y0f, 0.f), 1.f);
    float ax = fminf(fmaxf(fx - x0f, 0.f), 1.f);
    int y0 = (int)y0f, x0 = (int)x0f;
    const float* p00 = img + (((size_t)(b * 112 + y0) * 112 + x0) * 64) + lane;
    float v00 = p00[0], v01 = p00[64];
    float v10 = p00[112 * 64], v11 = p00[112 * 64 + 64];
    float top = v00 * (1.f - ax) + v01 * ax;
    float bot = v10 * (1.f - ax) + v11 * ax;
    tile[lane][xx] = top * (1.f - ay) + bot * ay;
  }
  __syncthreads();

  // phase C: coalesced NCHW write
  float* ob = out + (size_t)b * 64 * 12544 + y * 112;
  for (int i = 0; i < 28; ++i) {
    int idx = i * 256 + t;           // < 7168
    int c = idx / 112, xx = idx - c * 112;
    ob[(size_t)c * 12544 + xx] = tile[c][xx];
  }
}

extern "C" void kernel_launch(void* const* d_in, const int* in_sizes, int n_in,
                              void* d_out, int out_size, void* d_ws, size_t ws_size,
                              hipStream_t stream) {
  const float* x      = (const float*)d_in[0];
  const float* img    = (const float*)d_in[1];
  const float* scales = (const float*)d_in[2];
  const float* W1     = (const float*)d_in[3];
  const float* b1     = (const float*)d_in[4];
  const float* W2     = (const float*)d_in[5];
  const float* b2     = (const float*)d_in[6];
  const float* W3     = (const float*)d_in[7];
  const float* b3     = (const float*)d_in[8];
  const float* lmean  = (const float*)d_in[9];
  float* out = (float*)d_out;
  float* ws  = (float*)d_ws;

  float* P1   = ws;                        // 56*2048 floats
  float* P2   = P1 + (size_t)NSL * 2048;   // 2048
  float* COEF = P2 + 2048;                 // 16*80
  float* NORM = COEF + 16 * 80;            // 16

  k_gemm1<<<NSL * 16, 256, 0, stream>>>(x, W1, P1);
  k_red  <<<8, 256, 0, stream>>>(P1, P2);
  k_small<<<16, 64, 0, stream>>>(P2, b1, W2, b2, W3, b3, lmean, scales,
                                 out + PRED_OFF, COEF, NORM);
  k_warp <<<16 * 112, 256, 0, stream>>>(img, COEF, NORM, out);
}

// Round 7
// 243.565 us; speedup vs baseline: 2.2168x; 2.2168x over previous
//
#include <hip/hip_runtime.h>
#include <math.h>
#include <stdint.h>

#define F_K 802816          // 64*112*112
#define NWIN 1568           // k-windows (= grid)
#define WIN 512             // floats per window (8 tiles x 64)
#define NT 8                // tiles per window
#define PRED_OFF 12845056
#define NORM_OFF 12845568   // PRED_OFF + 512

#define AS3 __attribute__((address_space(3)))
#define AS1 __attribute__((address_space(1)))

// async global->LDS; dest = base + lane*size (HW), src per-lane.
__device__ __forceinline__ void gload16(const float* gsrc, float* ldsbase) {
  __builtin_amdgcn_global_load_lds((const AS1 uint32_t*)gsrc, (AS3 uint32_t*)ldsbase, 16, 0, 0);
}
__device__ __forceinline__ void gload4(const float* gsrc, float* ldsbase) {
  __builtin_amdgcn_global_load_lds((const AS1 uint32_t*)gsrc, (AS3 uint32_t*)ldsbase, 4, 0, 0);
}

// ---------------- Kernel 1: phase-rotated split-K GEMM -------------------------
// Block c covers k-window [c*512, (c+1)*512). W1/x row stride = 49*64KiB: all
// rows congruent mod 64KiB -> same-column reads across rows hit ONE channel
// granule. Fix: row n's tile for iteration t is column (t+(n&7))&7 of the
// window (per-row phase rotation) -> each staging call spans 8 granules.
// x chunk staged ONCE to LDS [T][b][68]+skew (x fetched exactly once chip-wide);
// compute reads x at the same shifted column (thread's rows share n mod 16).
// Wave w owns the 16-float k-quarter [16w,16w+16) of each tile; W staged
// wave-private with R4's cell rotation (2-way banks); barrier-free k-loop.
__global__ __launch_bounds__(256, 2) void k_gemm1(const float* __restrict__ x,
                                                  const float* __restrict__ w1,
                                                  float* __restrict__ part) {
  __shared__ __align__(16) float XL[8736];       // x: T*1092 + b*68 + f (34.9 KB)
  __shared__ __align__(16) float WS[4 * 2048];   // W: wave-private [128][16] rotated
  const int t = threadIdx.x;
  const int wave = t >> 6, lane = t & 63;
  const int nl = t & 15;
  const int bg = (t >> 4) & 3;
  const int c = blockIdx.x;
  const size_t base = (size_t)c * WIN;

  // ---- stage x chunk (once): 128 calls of 256B, call m covers (T=m>>4, b=m&15)
  for (int s = 0; s < 32; ++s) {
    int m = wave * 32 + s;
    int T = m >> 4, b = m & 15;
    gload4(x + (size_t)b * F_K + base + T * 64 + lane, XL + T * 1092 + b * 68);
  }

  // ---- W staging addresses: call cc covers rows [16cc,16cc+16), 4 lanes/row
  const float* wsrcb[8];
  int ph[8];
#pragma unroll
  for (int cc = 0; cc < 8; ++cc) {
    int f = cc * 64 + lane;             // 0..511
    int n = f >> 2, tau = f & 3;
    int qr = (tau - (n >> 1)) & 3;      // R4 cell rotation (2-way banks on read)
    wsrcb[cc] = w1 + (size_t)n * F_K + base + 16 * wave + 4 * qr;
    ph[cc] = n & 7;                     // per-row tile phase
  }
  float* wb = WS + wave * 2048;

  float acc[4][8];
#pragma unroll
  for (int i = 0; i < 4; ++i)
#pragma unroll
    for (int j = 0; j < 8; ++j) acc[i][j] = 0.f;

  // x fully staged before any compute
  asm volatile("s_waitcnt vmcnt(0)" ::: "memory");
  __syncthreads();

  const int Tl = nl & 7;                // thread's row-phase (rows share n mod 16)
  for (int kt = 0; kt < NT; ++kt) {
    // stage this wave's k-quarter of tile kt, row n at column (kt+ph)&7
#pragma unroll
    for (int cc = 0; cc < 8; ++cc)
      gload16(wsrcb[cc] + (((kt + ph[cc]) & 7) << 6), wb + cc * 256);
    asm volatile("s_waitcnt vmcnt(0)" ::: "memory");
    __builtin_amdgcn_sched_barrier(0);

    const int Tx = (kt + Tl) & 7;       // x tile slot for this thread's rows
    const int xo = Tx * 1092 + 16 * wave;
#pragma unroll
    for (int q = 0; q < 4; ++q) {
      float4 xv[4];
#pragma unroll
      for (int i = 0; i < 4; ++i)
        xv[i] = *reinterpret_cast<const float4*>(&XL[xo + (4 * bg + i) * 68 + 4 * q]);
      const int tw = (q + (nl >> 1)) & 3;
#pragma unroll
      for (int j = 0; j < 8; ++j) {
        float4 wv = *reinterpret_cast<const float4*>(&wb[(16 * j + nl) * 16 + 4 * tw]);
#pragma unroll
        for (int i = 0; i < 4; ++i) {
          acc[i][j] += xv[i].x * wv.x;
          acc[i][j] += xv[i].y * wv.y;
          acc[i][j] += xv[i].z * wv.z;
          acc[i][j] += xv[i].w * wv.w;
        }
      }
    }
    // wave-private W region: own reads must retire before next overwrite
    __builtin_amdgcn_sched_barrier(0);
    asm volatile("s_waitcnt lgkmcnt(0)" ::: "memory");
    __builtin_amdgcn_sched_barrier(0);
  }

  // cross-wave K reduction (reuse WS as red[4][2048])
  __syncthreads();
  float* red = WS;
#pragma unroll
  for (int i = 0; i < 4; ++i)
#pragma unroll
    for (int j = 0; j < 8; ++j)
      red[wave * 2048 + (4 * bg + i) * 128 + 16 * j + nl] = acc[i][j];
  __syncthreads();
  const int o8 = t * 8;
  float4 s0 = {0, 0, 0, 0}, s1 = {0, 0, 0, 0};
#pragma unroll
  for (int w = 0; w < 4; ++w) {
    float4 a = *reinterpret_cast<const float4*>(&red[w * 2048 + o8]);
    float4 b = *reinterpret_cast<const float4*>(&red[w * 2048 + o8 + 4]);
    s0.x += a.x; s0.y += a.y; s0.z += a.z; s0.w += a.w;
    s1.x += b.x; s1.y += b.y; s1.z += b.z; s1.w += b.w;
  }
  float* pp = part + (size_t)c * 2048 + o8;
  *reinterpret_cast<float4*>(pp) = s0;
  *reinterpret_cast<float4*>(pp + 4) = s1;
}

// ---------------- Kernel 2a: reduce 1568 window-partials -> p2[16][128] --------
__global__ __launch_bounds__(256) void k_red(const float* __restrict__ part,
                                             float* __restrict__ p2) {
  int idx = blockIdx.x * 256 + threadIdx.x;   // 0..2047
  const float* p = part + idx;
  float s = 0.f;
#pragma unroll 8
  for (int q = 0; q < NWIN; ++q) s += p[(size_t)q * 2048];
  p2[idx] = s;
}

// ---------------- Kernel 2b: small heads + TPS solve (1 wave / batch) ----------
__global__ __launch_bounds__(64) void k_small(const float* __restrict__ p2,
    const float* __restrict__ b1, const float* __restrict__ W2, const float* __restrict__ b2,
    const float* __restrict__ W3, const float* __restrict__ b3,
    const float* __restrict__ lmean, const float* __restrict__ scales,
    float* __restrict__ dout_pred, float* __restrict__ coef, float* __restrict__ norms) {
  const int b = blockIdx.x, lane = threadIdx.x;
  __shared__ float o[128], dflat[32], fl[32], A[19][22], farr[19], sol[19][2];

  o[lane]      = p2[b * 128 + lane]      + b1[lane];
  o[lane + 64] = p2[b * 128 + 64 + lane] + b1[64 + lane];
  __syncthreads();

  const int j = lane & 31;
  const float* Wm = (lane < 32) ? (W2 + j * 128) : (W3 + j * 128);
  float acc = 0.f;
#pragma unroll 4
  for (int n = 0; n < 128; ++n) acc += o[n] * Wm[n];
  float other = __shfl(acc, j + 32);
  float sc = scales[b];
  float dspv = 0.f;
  if (lane < 32) {
    float predv = acc + b2[j] + lmean[j];
    dspv = (other + b3[j]) * sc;
    dout_pred[b * 32 + j] = predv;
    dflat[j] = predv + dspv;   // dst (flat y,x pairs)
    fl[j] = dspv;              // flows = dst - src
  }
  float s2 = (lane < 32) ? dspv * dspv : 0.f;
  for (int off = 32; off; off >>= 1) s2 += __shfl_xor(s2, off);
  if (lane == 0) norms[b] = sqrtf(s2);
  __syncthreads();

  // build augmented TPS system A[19][19+2]
  for (int cell = lane; cell < 19 * 21; cell += 64) {
    int r = cell / 21, cc = cell - (cell / 21) * 21;
    float v;
    if (r < 16) {
      if (cc < 16) {
        float dy = dflat[2*r] - dflat[2*cc], dx = dflat[2*r+1] - dflat[2*cc+1];
        float d2 = dy * dy + dx * dx;
        v = 0.5f * d2 * logf(fmaxf(d2, 1e-10f));
        if (r == cc) v += 1e-6f;
      } else if (cc == 16) v = dflat[2*r];
      else if (cc == 17) v = dflat[2*r+1];
      else if (cc == 18) v = 1.0f;
      else if (cc == 19) v = fl[2*r];
      else               v = fl[2*r+1];
    } else {
      int rr = r - 16;
      if (cc < 16) v = (rr == 0) ? dflat[2*cc] : (rr == 1) ? dflat[2*cc+1] : 1.0f;
      else         v = 0.0f;
    }
    A[r][cc] = v;
  }
  __syncthreads();

  // Gaussian elimination with partial pivoting
  for (int k = 0; k < 19; ++k) {
    float av = (lane >= k && lane < 19) ? fabsf(A[lane][k]) : -1.0f;
    int idx = lane;
    for (int off = 32; off; off >>= 1) {
      float v2 = __shfl_xor(av, off);
      int  i2 = __shfl_xor(idx, off);
      if (v2 > av) { av = v2; idx = i2; }
    }
    idx = __shfl(idx, 0);
    if (idx != k && lane < 21) {
      float tmp = A[k][lane]; A[k][lane] = A[idx][lane]; A[idx][lane] = tmp;
    }
    __syncthreads();
    float invp = 1.0f / A[k][k];
    if (lane < 19) farr[lane] = (lane > k) ? A[lane][k] * invp : 0.0f;
    __syncthreads();
    int nr = 18 - k, nc = 20 - k;
    for (int cell = lane; cell < nr * nc; cell += 64) {
      int i = k + 1 + cell / nc, jj = k + 1 + cell % nc;
      A[i][jj] -= farr[i] * A[k][jj];
    }
    __syncthreads();
  }
  for (int k = 18; k >= 0; --k) {
    if (lane < 2) sol[k][lane] = A[k][19 + lane] / A[k][k];
    __syncthreads();
    if (lane < 2 * k) {
      int i = lane >> 1, cc = lane & 1;
      A[i][19 + cc] -= A[i][k] * sol[k][cc];
    }
    __syncthreads();
  }
  float* cf = coef + b * 80;
  if (lane < 32) { cf[lane] = sol[lane >> 1][lane & 1]; cf[38 + lane] = dflat[lane]; }
  else if (lane < 38) cf[lane] = sol[16 + ((lane - 32) >> 1)][(lane - 32) & 1];
}

// ---------------- Kernel 3: dense TPS flow + bilinear warp + NHWC->NCHW --------
__global__ __launch_bounds__(256) void k_warp(const float* __restrict__ img,
                                              const float* __restrict__ coef,
                                              const float* __restrict__ norms,
                                              float* __restrict__ out) {
  const int bid = blockIdx.x;
  const int b = bid / 112, y = bid - (bid / 112) * 112;
  const int t = threadIdx.x;
  __shared__ float qy[112], qx[112];
  __shared__ float cw[32], cv[6], cd[32];
  __shared__ float tile[64][113];

  if (bid == 0 && t == 0) {
    float s = 0.f;
    for (int i = 0; i < 16; ++i) s += norms[i];
    out[NORM_OFF] = s * (1.0f / 16.0f);
  }
  const float* cf = coef + b * 80;
  if (t < 70) {
    float v = cf[t];
    if (t < 32) cw[t] = v;
    else if (t < 38) cv[t - 32] = v;
    else cd[t - 38] = v;
  }
  __syncthreads();

  if (t < 112) {
    float fy = (float)y, fx = (float)t;
    float s0 = cv[0] * fy + cv[2] * fx + cv[4];
    float s1 = cv[1] * fy + cv[3] * fx + cv[5];
#pragma unroll
    for (int i = 0; i < 16; ++i) {
      float dy = fy - cd[2 * i], dx = fx - cd[2 * i + 1];
      float d2 = dy * dy + dx * dx;
      float ph = 0.5f * d2 * logf(fmaxf(d2, 1e-10f));
      s0 += ph * cw[2 * i];
      s1 += ph * cw[2 * i + 1];
    }
    qy[t] = fy - s0;
    qx[t] = fx - s1;
  }
  __syncthreads();

  const int wave = t >> 6, lane = t & 63;
#pragma unroll 4
  for (int p = 0; p < 28; ++p) {
    int xx = wave * 28 + p;
    float fy = qy[xx], fx = qx[xx];
    float y0f = fminf(fmaxf(floorf(fy), 0.f), 110.f);
    float x0f = fminf(fmaxf(floorf(fx), 0.f), 110.f);
    float ay = fminf(fmaxf(fy - y0f, 0.f), 1.f);
    float ax = fminf(fmaxf(fx - x0f, 0.f), 1.f);
    int y0 = (int)y0f, x0 = (int)x0f;
    const float* p00 = img + (((size_t)(b * 112 + y0) * 112 + x0) * 64) + lane;
    float v00 = p00[0], v01 = p00[64];
    float v10 = p00[112 * 64], v11 = p00[112 * 64 + 64];
    float top = v00 * (1.f - ax) + v01 * ax;
    float bot = v10 * (1.f - ax) + v11 * ax;
    tile[lane][xx] = top * (1.f - ay) + bot * ay;
  }
  __syncthreads();

  float* ob = out + (size_t)b * 64 * 12544 + y * 112;
  for (int i = 0; i < 28; ++i) {
    int idx = i * 256 + t;
    int cc = idx / 112, xx = idx - cc * 112;
    ob[(size_t)cc * 12544 + xx] = tile[cc][xx];
  }
}

extern "C" void kernel_launch(void* const* d_in, const int* in_sizes, int n_in,
                              void* d_out, int out_size, void* d_ws, size_t ws_size,
                              hipStream_t stream) {
  const float* x      = (const float*)d_in[0];
  const float* img    = (const float*)d_in[1];
  const float* scales = (const float*)d_in[2];
  const float* W1     = (const float*)d_in[3];
  const float* b1     = (const float*)d_in[4];
  const float* W2     = (const float*)d_in[5];
  const float* b2     = (const float*)d_in[6];
  const float* W3     = (const float*)d_in[7];
  const float* b3     = (const float*)d_in[8];
  const float* lmean  = (const float*)d_in[9];
  float* out = (float*)d_out;
  float* ws  = (float*)d_ws;

  float* P1   = ws;                        // 1568*2048 floats (12.85 MB)
  float* P2   = P1 + (size_t)NWIN * 2048;  // 2048
  float* COEF = P2 + 2048;                 // 16*80
  float* NORM = COEF + 16 * 80;            // 16

  k_gemm1<<<NWIN, 256, 0, stream>>>(x, W1, P1);
  k_red  <<<8, 256, 0, stream>>>(P1, P2);
  k_small<<<16, 64, 0, stream>>>(P2, b1, W2, b2, W3, b3, lmean, scales,
                                 out + PRED_OFF, COEF, NORM);
  k_warp <<<16 * 112, 256, 0, stream>>>(img, COEF, NORM, out);
}